// Round 6
// baseline (12153.329 us; speedup 1.0000x reference)
//
#include <hip/hip_runtime.h>

#define VOCABN 401
#define EN 256
#define HN 768
#define H3N 2304
#define ON 3
#define BN 64
#define TN 1024

// 16 replicas x 16 WGs; each WG: 48 j's, k split 8 ways, 4 batches
#define NREP 16
#define WGPR 16
#define BPR  4
#define JPW  48
#define NTH  384

typedef _Float16 f16x2 __attribute__((ext_vector_type(2)));
typedef _Float16 f16x8 __attribute__((ext_vector_type(8)));
typedef unsigned u32x4 __attribute__((ext_vector_type(4)));
union F16x8 { f16x8 v; f16x2 p[4]; };
union U4F8 { u32x4 u; f16x8 h; };

__device__ __forceinline__ float fdot2(f16x2 a, f16x2 b, float c) {
#if __has_builtin(__builtin_amdgcn_fdot2)
    return __builtin_amdgcn_fdot2(a, b, c, false);
#else
    return c + (float)a[0] * (float)b[0] + (float)a[1] * (float)b[1];
#endif
}
#define UMIN(a,b) ((a) < (b) ? (a) : (b))

// ---------------- K1: gtab[v][g] = dot(embed[v], W_ih[g]) + b_ih[g]
__global__ __launch_bounds__(256)
void k_build_gtab(const float* __restrict__ embed, const float* __restrict__ wih,
                  const float* __restrict__ bih, float* __restrict__ gtab) {
    const int g  = blockIdx.x * 64 + (threadIdx.x >> 2);
    const int ql = threadIdx.x & 3;
    const int v0 = blockIdx.y * 101;
    const int v1 = min(VOCABN, v0 + 101);
    float4 w[16];
    const float4* s4 = (const float4*)(wih + (size_t)g * EN + ql * 64);
#pragma unroll
    for (int i = 0; i < 16; ++i) w[i] = s4[i];
    const float bias = bih[g];
    for (int v = v0; v < v1; ++v) {
        const float4* e4 = (const float4*)(embed + (size_t)v * EN + ql * 64);
        float acc = 0.f;
#pragma unroll
        for (int i = 0; i < 16; ++i) {
            float4 e = e4[i];
            acc += w[i].x * e.x + w[i].y * e.y + w[i].z * e.z + w[i].w * e.w;
        }
        acc += __shfl_xor(acc, 1, 64);
        acc += __shfl_xor(acc, 2, 64);
        if (ql == 0) gtab[(size_t)v * H3N + g] = acc + bias;
    }
}

// ---------------- K2: persistent-weight recurrence, per-WG flag sync.
// Producer: store 384B h (f16) sc0/sc1 -> vmcnt(0) -> store flag=t+1.
// Consumer: tid0 polls the replica's 16 flags (one 64B line) >= t, barrier,
// then every thread does exactly ONE 16B data load. memset-0 == valid t=0.
__global__ __launch_bounds__(NTH, 1)
void k_rnn(const int* __restrict__ tokens, const float* __restrict__ whh,
           const float* __restrict__ gtab, const float* __restrict__ bhh,
           unsigned short* __restrict__ hbuf, unsigned* __restrict__ flags,
           float* __restrict__ hout) {
    const int R   = blockIdx.x & (NREP - 1);
    const int wg  = blockIdx.x >> 4;
    const int tid = threadIdx.x;
    const int jl  = tid >> 3;
    const int q   = tid & 7;
    const int j   = wg * JPW + jl;

    __shared__ int stok[BPR][TN];                          // 16384 B
    __shared__ __align__(16) _Float16 hlds[32 * 112];      // dot-input tile
    __shared__ __align__(16) _Float16 hstage[BPR * JPW];   // produced h (192 f16)

    for (int i = tid; i < BPR * TN; i += NTH)
        stok[i >> 10][i & 1023] = tokens[(size_t)(R * BPR + (i >> 10)) * TN + (i & 1023)];

    // ---- one-time: weight slice -> 36 statically-indexed f16x8
    F16x8 w[3][12];
#pragma unroll
    for (int g = 0; g < 3; ++g) {
        const float4* s4 = (const float4*)(whh + (size_t)(g * HN + j) * HN + q * 96);
#pragma unroll
        for (int c = 0; c < 12; ++c) {
            float4 a = s4[2 * c], b4 = s4[2 * c + 1];
            F16x8 t;
            t.v[0] = (_Float16)a.x;  t.v[1] = (_Float16)a.y;
            t.v[2] = (_Float16)a.z;  t.v[3] = (_Float16)a.w;
            t.v[4] = (_Float16)b4.x; t.v[5] = (_Float16)b4.y;
            t.v[6] = (_Float16)b4.z; t.v[7] = (_Float16)b4.w;
            w[g][c] = t;
        }
    }

    const float bhr = bhh[j], bhz = bhh[HN + j], bhn = bhh[2 * HN + j];
    unsigned short* hb = hbuf + (size_t)R * (2 * BPR * HN);   // f16 words
    unsigned* fb = flags + R * 16;                            // one 64B line

    // consumer mapping: thread covers f16 words [tid*8, tid*8+8)
    const int cb   = tid / 96;                // batch
    const int cr   = tid % 96;
    const int cs   = cr / 12;                 // q-slot (j0/96)
    const int coff = (cr % 12) * 8;           // j0%96
    _Float16* cdst = hlds + ((cb << 3) + cs) * 112 + coff;
    // producer mapping (tid<24): hstage f16 words [tid*8, tid*8+8)
    const int pb  = tid / 6;
    const int pj0 = (tid % 6) * 8;
    // per-batch LDS read bases
    const _Float16* hp0 = hlds + (0 * 8 + q) * 112;
    const _Float16* hp1 = hlds + (1 * 8 + q) * 112;
    const _Float16* hp2 = hlds + (2 * 8 + q) * 112;
    const _Float16* hp3 = hlds + (3 * 8 + q) * 112;

    float hprev = 0.f, xr = 0.f, xz = 0.f, xn = 0.f;
    __syncthreads();

    for (int t = 0; t < TN; ++t) {
        if (q < BPR) {                         // x-gate prefetch, overlaps the poll
            const float* g_ = gtab + (size_t)stok[q][t] * H3N;
            xr = g_[j]; xz = g_[HN + j]; xn = g_[2 * HN + j];
        }
        // ---- tid0 polls the 16 flags (64B, 4 x dwordx4 sc0 sc1) until min >= t
        if (tid == 0) {
            const unsigned want = (unsigned)t;
            for (;;) {
                u32x4 f0, f1, f2, f3;
                asm volatile(
                    "global_load_dwordx4 %0, %4, off sc0 sc1\n\t"
                    "global_load_dwordx4 %1, %5, off sc0 sc1\n\t"
                    "global_load_dwordx4 %2, %6, off sc0 sc1\n\t"
                    "global_load_dwordx4 %3, %7, off sc0 sc1\n\t"
                    "s_waitcnt vmcnt(0)"
                    : "=&v"(f0), "=&v"(f1), "=&v"(f2), "=&v"(f3)
                    : "v"(fb), "v"(fb + 4), "v"(fb + 8), "v"(fb + 12)
                    : "memory");
                unsigned mn = UMIN(UMIN(UMIN(f0[0], f0[1]), UMIN(f0[2], f0[3])),
                                   UMIN(UMIN(f1[0], f1[1]), UMIN(f1[2], f1[3])));
                mn = UMIN(mn, UMIN(UMIN(UMIN(f2[0], f2[1]), UMIN(f2[2], f2[3])),
                                   UMIN(UMIN(f3[0], f3[1]), UMIN(f3[2], f3[3]))));
                if (mn >= want) break;
            }
        }
        __syncthreads();                       // flags OK -> data valid at LLC

        // ---- exactly one 16B data load per thread, deposit to hlds
        {
            const unsigned short* src = hb + (t & 1) * (BPR * HN) + tid * 8;
            U4F8 d;
            asm volatile("global_load_dwordx4 %0, %1, off sc0 sc1\n\t"
                         "s_waitcnt vmcnt(0)"
                         : "=&v"(d.u) : "v"(src) : "memory");
            *(f16x8*)cdst = d.h;
        }
        __syncthreads();

        // ---- dot: c-outer (each weight reg read once), 12 live accumulators
        float ar[BPR], az[BPR], an[BPR];
#pragma unroll
        for (int b = 0; b < BPR; ++b) { ar[b] = 0.f; az[b] = 0.f; an[b] = 0.f; }
#pragma unroll
        for (int c = 0; c < 12; ++c) {
            const F16x8 w0 = w[0][c], w1 = w[1][c], w2 = w[2][c];
#pragma unroll
            for (int b = 0; b < BPR; ++b) {
                const _Float16* hp = (b == 0) ? hp0 : (b == 1) ? hp1 : (b == 2) ? hp2 : hp3;
                F16x8 hh; hh.v = ((const f16x8*)hp)[c];
#pragma unroll
                for (int p = 0; p < 4; ++p) {
                    ar[b] = fdot2(w0.p[p], hh.p[p], ar[b]);
                    az[b] = fdot2(w1.p[p], hh.p[p], az[b]);
                    an[b] = fdot2(w2.p[p], hh.p[p], an[b]);
                }
            }
        }
#pragma unroll
        for (int b = 0; b < BPR; ++b) {
            ar[b] += __shfl_xor(ar[b], 1, 64); ar[b] += __shfl_xor(ar[b], 2, 64); ar[b] += __shfl_xor(ar[b], 4, 64);
            az[b] += __shfl_xor(az[b], 1, 64); az[b] += __shfl_xor(az[b], 2, 64); az[b] += __shfl_xor(az[b], 4, 64);
            an[b] += __shfl_xor(an[b], 1, 64); an[b] += __shfl_xor(an[b], 2, 64); an[b] += __shfl_xor(an[b], 4, 64);
            if (q == b) {
                const float r  = 1.f / (1.f + __expf(-(xr + ar[b] + bhr)));
                const float z  = 1.f / (1.f + __expf(-(xz + az[b] + bhz)));
                const float nx = xn + r * (an[b] + bhn);
                const float n  = 1.f - 2.f / (__expf(2.f * nx) + 1.f);   // tanh
                hprev = (1.f - z) * n + z * hprev;
                if (t < TN - 1) hstage[b * JPW + jl] = (_Float16)hprev;
                else            hout[(size_t)(R * BPR + b) * HN + j] = hprev;
            }
        }
        if (t < TN - 1) {
            __syncthreads();                   // hstage complete; hlds reads done
            if (tid < 24) {                    // 24 threads x 16B = this WG's 384B
                u32x4 val = *(const u32x4*)(hstage + tid * 8);
                unsigned short* dst = hb + ((t + 1) & 1) * (BPR * HN)
                                    + pb * HN + wg * JPW + pj0;
                asm volatile("global_store_dwordx4 %0, %1, off sc0 sc1"
                             :: "v"(dst), "v"(val) : "memory");
            }
            if (tid < 64) {                    // wave 0: ack stores, then flag
                asm volatile("s_waitcnt vmcnt(0)" ::: "memory");
                if (tid == 0) {
                    unsigned fv = (unsigned)(t + 1);
                    asm volatile("global_store_dword %0, %1, off sc0 sc1"
                                 :: "v"(fb + wg), "v"(fv) : "memory");
                }
            }
        }
    }
}

// ---------------- K3: logits + log_softmax
__global__ void k_logits(const float* __restrict__ hfin, const float* __restrict__ wout,
                         const float* __restrict__ bout, float* __restrict__ lp) {
    const int b = blockIdx.x;
    const int o = threadIdx.x / 64;
    const int lane = threadIdx.x % 64;
    const float* hrow = hfin + (size_t)b * HN;
    const float* w = wout + (size_t)o * HN;
    float p = 0.f;
    for (int k = lane; k < HN; k += 64) p += hrow[k] * w[k];
    for (int off = 32; off > 0; off >>= 1) p += __shfl_down(p, off, 64);
    __shared__ float lg[ON];
    if (lane == 0) lg[o] = p + bout[o];
    __syncthreads();
    if (threadIdx.x == 0) {
        float m = fmaxf(lg[0], fmaxf(lg[1], lg[2]));
        float s = __expf(lg[0] - m) + __expf(lg[1] - m) + __expf(lg[2] - m);
        float ls = __logf(s);
        lp[b * ON + 0] = lg[0] - m - ls;
        lp[b * ON + 1] = lg[1] - m - ls;
        lp[b * ON + 2] = lg[2] - m - ls;
    }
}

extern "C" void kernel_launch(void* const* d_in, const int* in_sizes, int n_in,
                              void* d_out, int out_size, void* d_ws, size_t ws_size,
                              hipStream_t stream) {
    const int*   tokens = (const int*)d_in[0];
    // d_in[1] = hidden: reference zeroes it, ignored.
    const float* embed  = (const float*)d_in[2];
    const float* wih    = (const float*)d_in[3];
    const float* whh    = (const float*)d_in[4];
    const float* bih    = (const float*)d_in[5];
    const float* bhh    = (const float*)d_in[6];
    const float* wout   = (const float*)d_in[7];
    const float* bout   = (const float*)d_in[8];

    float* out = (float*)d_out;                   // [B*O logprobs][B*H h_final]
    char* ws = (char*)d_ws;
    const size_t GTAB_OFF  = 0;                   // 401*2304*4 = 3,695,616
    const size_t HBUF_OFF  = 3695616;             // 16*2*3072*2 = 196,608 (f16)
    const size_t FLAGS_OFF = HBUF_OFF + 196608;   // 16*16*4 = 1,024
    float*          gtab  = (float*)(ws + GTAB_OFF);
    unsigned short* hbuf  = (unsigned short*)(ws + HBUF_OFF);
    unsigned*       flags = (unsigned*)(ws + FLAGS_OFF);

    // protocol requires zeros (h0 + flags) on EVERY launch (graph-replayed)
    hipMemsetAsync(ws + HBUF_OFF, 0, 196608 + 1024, stream);

    hipLaunchKernelGGL(k_build_gtab, dim3(H3N / 64, 4), dim3(256), 0, stream,
                       embed, wih, bih, gtab);
    hipLaunchKernelGGL(k_rnn, dim3(NREP * WGPR), dim3(NTH), 0, stream,
                       tokens, whh, gtab, bhh, hbuf, flags, out + BN * ON);
    hipLaunchKernelGGL(k_logits, dim3(BN), dim3(192), 0, stream,
                       out + BN * ON, wout, bout, out);
}